// Round 2
// baseline (390.463 us; speedup 1.0000x reference)
//
#include <hip/hip_runtime.h>
#include <stdint.h>

#define BATCH 8
#define MPTS 500000
#define NPTS (BATCH * MPTS)            // 4,000,000
#define NBQ 4096                       // buckets = 8 batches * 8*8*8 sub-blocks
#define TP 8192                        // points per tile
#define NTILE ((NPTS + TP - 1) / TP)   // 489

// bucket id + local voxel id (16^3 sub-block) for point p
__device__ __forceinline__ int point_bucket(const int* __restrict__ idx, int p, int& l) {
    int b = p / MPTS;
    const int* t = idx + p * 3;
    int i = t[0], j = t[1], k = t[2];
    l = ((i & 15) << 8) | ((j & 15) << 4) | (k & 15);
    return (b << 9) + ((i >> 4) << 6) + ((j >> 4) << 3) + (k >> 4);
}

__device__ __forceinline__ void block_reduce2(float& tv, float& mse) {
    for (int off = 32; off > 0; off >>= 1) {
        tv  += __shfl_down(tv, off, 64);
        mse += __shfl_down(mse, off, 64);
    }
    __shared__ float stv[4], sms[4];
    int w = threadIdx.x >> 6, lane = threadIdx.x & 63;
    if (lane == 0) { stv[w] = tv; sms[w] = mse; }
    __syncthreads();
    if (threadIdx.x == 0) {
        tv  = stv[0] + stv[1] + stv[2] + stv[3];
        mse = sms[0] + sms[1] + sms[2] + sms[3];
    }
}

// K1: per-tile bucket histogram (LDS), write full row per tile
__global__ void __launch_bounds__(256) hist_k(const int* __restrict__ idx,
                                              uint32_t* __restrict__ hist) {
    __shared__ uint32_t h[NBQ];
    for (int c = threadIdx.x; c < NBQ; c += 256) h[c] = 0;
    __syncthreads();
    int tile = blockIdx.x;
    int p0 = tile * TP;
    int cnt = min(TP, NPTS - p0);
    for (int r = threadIdx.x; r < cnt; r += 256) {
        int l, q = point_bucket(idx, p0 + r, l);
        atomicAdd(&h[q], 1u);
    }
    __syncthreads();
    uint32_t* outrow = hist + (size_t)tile * NBQ;
    for (int c = threadIdx.x; c < NBQ; c += 256) outrow[c] = h[c];
}

// K2: per-bucket exclusive scan over tiles (in place); per-bucket totals
__global__ void __launch_bounds__(256) scan_tiles_k(uint32_t* __restrict__ hist,
                                                    uint32_t* __restrict__ totals) {
    int q = blockIdx.x * 256 + threadIdx.x;   // 16 blocks x 256 = 4096
    uint32_t run = 0;
    #pragma unroll 4
    for (int t = 0; t < NTILE; ++t) {
        uint32_t h = hist[(size_t)t * NBQ + q];
        hist[(size_t)t * NBQ + q] = run;
        run += h;
    }
    totals[q] = run;
}

// K3: exclusive scan of 4096 totals -> base (single block)
__global__ void __launch_bounds__(256) scan_base_k(const uint32_t* __restrict__ totals,
                                                   uint32_t* __restrict__ base) {
    __shared__ uint32_t ssum[256];
    uint32_t loc[16];
    int q0 = threadIdx.x * 16;
    uint32_t s = 0;
    #pragma unroll
    for (int e = 0; e < 16; ++e) { loc[e] = totals[q0 + e]; s += loc[e]; }
    ssum[threadIdx.x] = s;
    __syncthreads();
    for (int off = 1; off < 256; off <<= 1) {
        uint32_t v = 0;
        if (threadIdx.x >= off) v = ssum[threadIdx.x - off];
        __syncthreads();
        if (threadIdx.x >= off) ssum[threadIdx.x] += v;
        __syncthreads();
    }
    uint32_t run = threadIdx.x ? ssum[threadIdx.x - 1] : 0;
    #pragma unroll
    for (int e = 0; e < 16; ++e) { base[q0 + e] = run; run += loc[e]; }
}

// K4: reorder points into bucket-contiguous records (LDS cursors, no global atomics)
__global__ void __launch_bounds__(256) reorder_k(const int* __restrict__ idx,
                                                 const float* __restrict__ val,
                                                 const uint32_t* __restrict__ hist,
                                                 const uint32_t* __restrict__ base,
                                                 uint2* __restrict__ rec) {
    __shared__ uint32_t cur[NBQ];
    int tile = blockIdx.x;
    const uint32_t* offrow = hist + (size_t)tile * NBQ;
    for (int c = threadIdx.x; c < NBQ; c += 256) cur[c] = base[c] + offrow[c];
    __syncthreads();
    int p0 = tile * TP;
    int cnt = min(TP, NPTS - p0);
    for (int r = threadIdx.x; r < cnt; r += 256) {
        int p = p0 + r;
        int l, q = point_bucket(idx, p, l);
        float v = val[p];
        uint32_t pos = atomicAdd(&cur[q], 1u);
        rec[pos] = make_uint2((uint32_t)l, __float_as_uint(v));
    }
}

// K5: per-bucket LDS accumulate + interior TV/MSE + emit 6 boundary faces
__global__ void __launch_bounds__(256) accum_k(const uint2* __restrict__ rec,
                                               const uint32_t* __restrict__ base,
                                               const uint32_t* __restrict__ totals,
                                               float* __restrict__ faces,
                                               float* __restrict__ out) {
    __shared__ float g[4096];   // 16^3 sub-block
    int q = blockIdx.x;
    for (int c = threadIdx.x; c < 4096; c += 256) g[c] = 0.f;
    __syncthreads();
    uint32_t s0 = base[q], cnt = totals[q];
    for (uint32_t r = threadIdx.x; r < cnt; r += 256) {
        uint2 e = rec[s0 + r];
        atomicAdd(&g[e.x], __uint_as_float(e.y));
    }
    __syncthreads();
    float tv = 0.f, mse = 0.f;
    for (int l = threadIdx.x; l < 4096; l += 256) {
        float c = g[l];
        int k = l & 15, j = (l >> 4) & 15, i = l >> 8;
        if (i < 15) { float d = g[l + 256] - c; tv += fabsf(d); mse += d * d; }
        if (j < 15) { float d = g[l + 16]  - c; tv += fabsf(d); mse += d * d; }
        if (k < 15) { float d = g[l + 1]   - c; tv += fabsf(d); mse += d * d; }
    }
    // boundary faces: [q][face 0..5][256]
    {
        float* f = faces + (size_t)q * 1536;
        int t = threadIdx.x;           // 256 threads, one element per face each
        int hi = t >> 4, lo = t & 15;
        f[t]        = g[t];                        // i=0  (e = j*16+k)
        f[256 + t]  = g[3840 + t];                 // i=15
        f[512 + t]  = g[hi * 256 + lo];            // j=0  (e = i*16+k)
        f[768 + t]  = g[hi * 256 + 240 + lo];      // j=15
        f[1024 + t] = g[hi * 256 + lo * 16];       // k=0  (e = i*16+j)
        f[1280 + t] = g[hi * 256 + lo * 16 + 15];  // k=15
    }
    block_reduce2(tv, mse);
    if (threadIdx.x == 0) {
        int b = q >> 9;
        atomicAdd(&out[b],     tv  * (1.f / 2097152.f));   // / X^3
        atomicAdd(&out[8 + b], mse * (1.f / 32512.f));     // / (2X^2-2X)
    }
}

// K6: cross-sub-block interface diffs from face arrays
// block = ((axis*8 + b)*7 + s)*8 + u  -> 3*8*7*8 = 1344 blocks, 8 face-pairs each
__global__ void __launch_bounds__(256) boundary_k(const float* __restrict__ faces,
                                                  float* __restrict__ out) {
    int x = blockIdx.x;
    int u = x & 7;
    int r = x >> 3;
    int s = r % 7;
    int rb = r / 7;
    int b = rb & 7;
    int axis = rb >> 3;
    float tv = 0.f, mse = 0.f;
    for (int w = threadIdx.x; w < 2048; w += 256) {
        int v = w >> 8;
        int e = w & 255;
        int qA, qB, fA, fB;
        if (axis == 0)      { qA = (b<<9) + (s<<6) + (u<<3) + v; qB = qA + 64; fA = 256;  fB = 0;    }
        else if (axis == 1) { qA = (b<<9) + (u<<6) + (s<<3) + v; qB = qA + 8;  fA = 768;  fB = 512;  }
        else                { qA = (b<<9) + (u<<6) + (v<<3) + s; qB = qA + 1;  fA = 1280; fB = 1024; }
        float d = faces[(size_t)qB * 1536 + fB + e] - faces[(size_t)qA * 1536 + fA + e];
        tv += fabsf(d); mse += d * d;
    }
    block_reduce2(tv, mse);
    if (threadIdx.x == 0) {
        atomicAdd(&out[b],     tv  * (1.f / 2097152.f));
        atomicAdd(&out[8 + b], mse * (1.f / 32512.f));
    }
}

extern "C" void kernel_launch(void* const* d_in, const int* in_sizes, int n_in,
                              void* d_out, int out_size, void* d_ws, size_t ws_size,
                              hipStream_t stream) {
    const int*   indices = (const int*)d_in[0];   // (B, M, 3) int32
    const float* values  = (const float*)d_in[1]; // (B, M) float32
    float*       out     = (float*)d_out;         // (2, B) float32

    // workspace layout (62.2 MiB total, < 64 MiB proven available)
    uint32_t* hist   = (uint32_t*)d_ws;                       // NTILE*NBQ  (8.0 MB)
    uint32_t* totals = hist + (size_t)NTILE * NBQ;            // NBQ
    uint32_t* base   = totals + NBQ;                          // NBQ
    uint2*    rec    = (uint2*)(base + NBQ);                  // NPTS       (32 MB)
    float*    faces  = (float*)(rec + NPTS);                  // NBQ*1536   (25.2 MB)

    hipMemsetAsync(out, 0, (size_t)out_size * sizeof(float), stream);

    hist_k      <<<NTILE,     256, 0, stream>>>(indices, hist);
    scan_tiles_k<<<NBQ / 256, 256, 0, stream>>>(hist, totals);
    scan_base_k <<<1,         256, 0, stream>>>(totals, base);
    reorder_k   <<<NTILE,     256, 0, stream>>>(indices, values, hist, base, rec);
    accum_k     <<<NBQ,       256, 0, stream>>>(rec, base, totals, faces, out);
    boundary_k  <<<1344,      256, 0, stream>>>(faces, out);
}

// Round 3
// 260.402 us; speedup vs baseline: 1.4995x; 1.4995x over previous
//
#include <hip/hip_runtime.h>
#include <stdint.h>

#define BATCH 8
#define MPTS 500000
#define NPTS (BATCH * MPTS)            // 4,000,000
#define NBQ 4096                       // buckets = 8 batches * 8*8*8 sub-blocks
#define TP 8192                        // points per tile
#define NTILE ((NPTS + TP - 1) / TP)   // 489
#define NBND 1344                      // boundary blocks: 8 batches * 3 axes * 7 * 8

// bucket id + local voxel id (16^3 sub-block) for point p
__device__ __forceinline__ int point_bucket(const int* __restrict__ idx, int p, int& l) {
    int b = p / MPTS;
    const int* t = idx + p * 3;
    int i = t[0], j = t[1], k = t[2];
    l = ((i & 15) << 8) | ((j & 15) << 4) | (k & 15);
    return (b << 9) + ((i >> 4) << 6) + ((j >> 4) << 3) + (k >> 4);
}

// leaves block totals in thread 0's (tv, mse)
__device__ __forceinline__ void block_reduce2(float& tv, float& mse) {
    for (int off = 32; off > 0; off >>= 1) {
        tv  += __shfl_down(tv, off, 64);
        mse += __shfl_down(mse, off, 64);
    }
    __shared__ float stv[4], sms[4];
    int w = threadIdx.x >> 6, lane = threadIdx.x & 63;
    if (lane == 0) { stv[w] = tv; sms[w] = mse; }
    __syncthreads();
    if (threadIdx.x == 0) {
        tv  = stv[0] + stv[1] + stv[2] + stv[3];
        mse = sms[0] + sms[1] + sms[2] + sms[3];
    }
}

// K1: per-tile bucket histogram (LDS), write full row per tile
__global__ void __launch_bounds__(256) hist_k(const int* __restrict__ idx,
                                              uint32_t* __restrict__ hist) {
    __shared__ uint32_t h[NBQ];
    for (int c = threadIdx.x; c < NBQ; c += 256) h[c] = 0;
    __syncthreads();
    int tile = blockIdx.x;
    int p0 = tile * TP;
    int cnt = min(TP, NPTS - p0);
    for (int r = threadIdx.x; r < cnt; r += 256) {
        int l, q = point_bucket(idx, p0 + r, l);
        atomicAdd(&h[q], 1u);
    }
    __syncthreads();
    uint32_t* outrow = hist + (size_t)tile * NBQ;
    for (int c = threadIdx.x; c < NBQ; c += 256) outrow[c] = h[c];
}

// K2: per-bucket exclusive scan over tiles (in place); per-bucket totals
__global__ void __launch_bounds__(256) scan_tiles_k(uint32_t* __restrict__ hist,
                                                    uint32_t* __restrict__ totals) {
    int q = blockIdx.x * 256 + threadIdx.x;   // 16 blocks x 256 = 4096
    uint32_t run = 0;
    #pragma unroll 4
    for (int t = 0; t < NTILE; ++t) {
        uint32_t h = hist[(size_t)t * NBQ + q];
        hist[(size_t)t * NBQ + q] = run;
        run += h;
    }
    totals[q] = run;
}

// K3: exclusive scan of 4096 totals -> base (single block)
__global__ void __launch_bounds__(256) scan_base_k(const uint32_t* __restrict__ totals,
                                                   uint32_t* __restrict__ base) {
    __shared__ uint32_t ssum[256];
    uint32_t loc[16];
    int q0 = threadIdx.x * 16;
    uint32_t s = 0;
    #pragma unroll
    for (int e = 0; e < 16; ++e) { loc[e] = totals[q0 + e]; s += loc[e]; }
    ssum[threadIdx.x] = s;
    __syncthreads();
    for (int off = 1; off < 256; off <<= 1) {
        uint32_t v = 0;
        if (threadIdx.x >= off) v = ssum[threadIdx.x - off];
        __syncthreads();
        if (threadIdx.x >= off) ssum[threadIdx.x] += v;
        __syncthreads();
    }
    uint32_t run = threadIdx.x ? ssum[threadIdx.x - 1] : 0;
    #pragma unroll
    for (int e = 0; e < 16; ++e) { base[q0 + e] = run; run += loc[e]; }
}

// K4: reorder points into bucket-contiguous records (LDS cursors, no global atomics)
__global__ void __launch_bounds__(256) reorder_k(const int* __restrict__ idx,
                                                 const float* __restrict__ val,
                                                 const uint32_t* __restrict__ hist,
                                                 const uint32_t* __restrict__ base,
                                                 uint2* __restrict__ rec) {
    __shared__ uint32_t cur[NBQ];
    int tile = blockIdx.x;
    const uint32_t* offrow = hist + (size_t)tile * NBQ;
    for (int c = threadIdx.x; c < NBQ; c += 256) cur[c] = base[c] + offrow[c];
    __syncthreads();
    int p0 = tile * TP;
    int cnt = min(TP, NPTS - p0);
    for (int r = threadIdx.x; r < cnt; r += 256) {
        int p = p0 + r;
        int l, q = point_bucket(idx, p, l);
        float v = val[p];
        uint32_t pos = atomicAdd(&cur[q], 1u);
        rec[pos] = make_uint2((uint32_t)l, __float_as_uint(v));
    }
}

// K5: per-bucket LDS accumulate + interior TV/MSE partial + emit 6 boundary faces
__global__ void __launch_bounds__(256) accum_k(const uint2* __restrict__ rec,
                                               const uint32_t* __restrict__ base,
                                               const uint32_t* __restrict__ totals,
                                               float* __restrict__ faces,
                                               float2* __restrict__ pa) {
    __shared__ float g[4096];   // 16^3 sub-block
    int q = blockIdx.x;
    for (int c = threadIdx.x; c < 4096; c += 256) g[c] = 0.f;
    __syncthreads();
    uint32_t s0 = base[q], cnt = totals[q];
    for (uint32_t r = threadIdx.x; r < cnt; r += 256) {
        uint2 e = rec[s0 + r];
        atomicAdd(&g[e.x], __uint_as_float(e.y));
    }
    __syncthreads();
    float tv = 0.f, mse = 0.f;
    for (int l = threadIdx.x; l < 4096; l += 256) {
        float c = g[l];
        int k = l & 15, j = (l >> 4) & 15, i = l >> 8;
        if (i < 15) { float d = g[l + 256] - c; tv += fabsf(d); mse += d * d; }
        if (j < 15) { float d = g[l + 16]  - c; tv += fabsf(d); mse += d * d; }
        if (k < 15) { float d = g[l + 1]   - c; tv += fabsf(d); mse += d * d; }
    }
    // boundary faces: [q][face 0..5][256]
    {
        float* f = faces + (size_t)q * 1536;
        int t = threadIdx.x;           // 256 threads, one element per face each
        int hi = t >> 4, lo = t & 15;
        f[t]        = g[t];                        // i=0  (e = j*16+k)
        f[256 + t]  = g[3840 + t];                 // i=15
        f[512 + t]  = g[hi * 256 + lo];            // j=0  (e = i*16+k)
        f[768 + t]  = g[hi * 256 + 240 + lo];      // j=15
        f[1024 + t] = g[hi * 256 + lo * 16];       // k=0  (e = i*16+j)
        f[1280 + t] = g[hi * 256 + lo * 16 + 15];  // k=15
    }
    block_reduce2(tv, mse);
    if (threadIdx.x == 0) pa[q] = make_float2(tv, mse);   // no global atomics
}

// K6: cross-sub-block interface diffs from face arrays
// block x = ((b*3 + axis)*7 + s)*8 + u  (batch-major so partials are contiguous per b)
__global__ void __launch_bounds__(256) boundary_k(const float* __restrict__ faces,
                                                  float2* __restrict__ pb) {
    int x = blockIdx.x;
    int u = x & 7;
    int r = x >> 3;
    int s = r % 7;
    int t = r / 7;
    int axis = t % 3;
    int b = t / 3;
    float tv = 0.f, mse = 0.f;
    for (int w = threadIdx.x; w < 2048; w += 256) {
        int v = w >> 8;
        int e = w & 255;
        int qA, qB, fA, fB;
        if (axis == 0)      { qA = (b<<9) + (s<<6) + (u<<3) + v; qB = qA + 64; fA = 256;  fB = 0;    }
        else if (axis == 1) { qA = (b<<9) + (u<<6) + (s<<3) + v; qB = qA + 8;  fA = 768;  fB = 512;  }
        else                { qA = (b<<9) + (u<<6) + (v<<3) + s; qB = qA + 1;  fA = 1280; fB = 1024; }
        float d = faces[(size_t)qB * 1536 + fB + e] - faces[(size_t)qA * 1536 + fA + e];
        tv += fabsf(d); mse += d * d;
    }
    block_reduce2(tv, mse);
    if (threadIdx.x == 0) pb[x] = make_float2(tv, mse);   // no global atomics
}

// K7: final reduction — one block per batch, writes out directly, no atomics
__global__ void __launch_bounds__(256) final_k(const float2* __restrict__ pa,
                                               const float2* __restrict__ pb,
                                               float* __restrict__ out) {
    int b = blockIdx.x;
    float tv = 0.f, mse = 0.f;
    const float2* a = pa + (size_t)b * 512;
    for (int i = threadIdx.x; i < 512; i += 256) { float2 v = a[i]; tv += v.x; mse += v.y; }
    const float2* p = pb + (size_t)b * 168;
    for (int i = threadIdx.x; i < 168; i += 256) { float2 v = p[i]; tv += v.x; mse += v.y; }
    block_reduce2(tv, mse);
    if (threadIdx.x == 0) {
        out[b]     = tv  * (1.f / 2097152.f);   // / X^3
        out[8 + b] = mse * (1.f / 32512.f);     // / (2X^2-2X)
    }
}

extern "C" void kernel_launch(void* const* d_in, const int* in_sizes, int n_in,
                              void* d_out, int out_size, void* d_ws, size_t ws_size,
                              hipStream_t stream) {
    const int*   indices = (const int*)d_in[0];   // (B, M, 3) int32
    const float* values  = (const float*)d_in[1]; // (B, M) float32
    float*       out     = (float*)d_out;         // (2, B) float32

    // workspace layout (~62.3 MiB total; round-1 proved >= 64 MiB available)
    uint32_t* hist   = (uint32_t*)d_ws;                       // NTILE*NBQ   (8.0 MB)
    uint32_t* totals = hist + (size_t)NTILE * NBQ;            // NBQ
    uint32_t* base   = totals + NBQ;                          // NBQ
    uint2*    rec    = (uint2*)(base + NBQ);                  // NPTS        (32 MB)
    float*    faces  = (float*)(rec + NPTS);                  // NBQ*1536    (25.2 MB)
    float2*   pa     = (float2*)(faces + (size_t)NBQ * 1536); // NBQ         (32 KB)
    float2*   pb     = pa + NBQ;                              // NBND        (10.5 KB)

    hist_k      <<<NTILE,     256, 0, stream>>>(indices, hist);
    scan_tiles_k<<<NBQ / 256, 256, 0, stream>>>(hist, totals);
    scan_base_k <<<1,         256, 0, stream>>>(totals, base);
    reorder_k   <<<NTILE,     256, 0, stream>>>(indices, values, hist, base, rec);
    accum_k     <<<NBQ,       256, 0, stream>>>(rec, base, totals, faces, pa);
    boundary_k  <<<NBND,      256, 0, stream>>>(faces, pb);
    final_k     <<<BATCH,     256, 0, stream>>>(pa, pb, out);
}

// Round 4
// 204.237 us; speedup vs baseline: 1.9118x; 1.2750x over previous
//
#include <hip/hip_runtime.h>
#include <stdint.h>

#define BATCH 8
#define MPTS 500000
#define NPTS (BATCH * MPTS)            // 4,000,000
#define NBQ 4096                       // buckets = 8 batches * 8*8*8 sub-blocks
#define TP 16384                       // points per tile
#define NTILE ((NPTS + TP - 1) / TP)   // 245
#define NTPAD 256                      // padded tile rows (pad rows zeroed)
#define NBND 1344                      // boundary blocks: 8 batches * 3 axes * 7 * 8

// leaves block totals in thread 0's (tv, mse); for 256-thread blocks
__device__ __forceinline__ void block_reduce2(float& tv, float& mse) {
    for (int off = 32; off > 0; off >>= 1) {
        tv  += __shfl_down(tv, off, 64);
        mse += __shfl_down(mse, off, 64);
    }
    __shared__ float stv[4], sms[4];
    int w = threadIdx.x >> 6, lane = threadIdx.x & 63;
    if (lane == 0) { stv[w] = tv; sms[w] = mse; }
    __syncthreads();
    if (threadIdx.x == 0) {
        tv  = stv[0] + stv[1] + stv[2] + stv[3];
        mse = sms[0] + sms[1] + sms[2] + sms[3];
    }
}

// K1: per-tile bucket histogram (LDS) + packed (bucket,local) aux per point
__global__ void __launch_bounds__(1024) hist_k(const int* __restrict__ idx,
                                               uint32_t* __restrict__ hist,
                                               uint32_t* __restrict__ aux) {
    __shared__ uint32_t h[NBQ];
    for (int c = threadIdx.x; c < NBQ; c += 1024) h[c] = 0;
    __syncthreads();
    int tile = blockIdx.x;
    int p0 = tile * TP;
    int cnt = min(TP, NPTS - p0);
    for (int r = threadIdx.x; r < cnt; r += 1024) {
        int p = p0 + r;
        int b = p / MPTS;
        const int* t = idx + (size_t)p * 3;
        int i = t[0], j = t[1], k = t[2];
        int l = ((i & 15) << 8) | ((j & 15) << 4) | (k & 15);
        int q = (b << 9) + ((i >> 4) << 6) + ((j >> 4) << 3) + (k >> 4);
        aux[p] = ((uint32_t)q << 12) | (uint32_t)l;
        atomicAdd(&h[q], 1u);
    }
    __syncthreads();
    uint32_t* row = hist + (size_t)tile * NBQ;
    for (int c = threadIdx.x; c < NBQ; c += 1024) row[c] = h[c];
}

// K2: per-bucket exclusive scan over tile rows (in place), 16-way load batching
// to pipeline the latency chain. Pad rows [NTILE, NTPAD) must be zero.
__global__ void __launch_bounds__(256) scan_tiles_k(uint32_t* __restrict__ hist,
                                                    uint32_t* __restrict__ totals) {
    int q = blockIdx.x * 256 + threadIdx.x;   // 16 blocks x 256 = 4096
    uint32_t run = 0;
    for (int t0 = 0; t0 < NTPAD; t0 += 16) {
        uint32_t v[16];
        #pragma unroll
        for (int e = 0; e < 16; ++e) v[e] = hist[(size_t)(t0 + e) * NBQ + q];
        #pragma unroll
        for (int e = 0; e < 16; ++e) {
            uint32_t hh = v[e];
            hist[(size_t)(t0 + e) * NBQ + q] = run;
            run += hh;
        }
    }
    totals[q] = run;
}

// K3: exclusive scan of 4096 totals -> base (single block)
__global__ void __launch_bounds__(256) scan_base_k(const uint32_t* __restrict__ totals,
                                                   uint32_t* __restrict__ base) {
    __shared__ uint32_t ssum[256];
    uint32_t loc[16];
    int q0 = threadIdx.x * 16;
    uint32_t s = 0;
    #pragma unroll
    for (int e = 0; e < 16; ++e) { loc[e] = totals[q0 + e]; s += loc[e]; }
    ssum[threadIdx.x] = s;
    __syncthreads();
    for (int off = 1; off < 256; off <<= 1) {
        uint32_t v = 0;
        if (threadIdx.x >= off) v = ssum[threadIdx.x - off];
        __syncthreads();
        if (threadIdx.x >= off) ssum[threadIdx.x] += v;
        __syncthreads();
    }
    uint32_t run = threadIdx.x ? ssum[threadIdx.x - 1] : 0;
    #pragma unroll
    for (int e = 0; e < 16; ++e) { base[q0 + e] = run; run += loc[e]; }
}

// K4: reorder points into bucket-contiguous records (LDS cursors, no global atomics)
__global__ void __launch_bounds__(1024) reorder_k(const uint32_t* __restrict__ aux,
                                                  const float* __restrict__ val,
                                                  const uint32_t* __restrict__ hist,
                                                  const uint32_t* __restrict__ base,
                                                  uint2* __restrict__ rec) {
    __shared__ uint32_t cur[NBQ];
    int tile = blockIdx.x;
    const uint32_t* offrow = hist + (size_t)tile * NBQ;
    for (int c = threadIdx.x; c < NBQ; c += 1024) cur[c] = base[c] + offrow[c];
    __syncthreads();
    int p0 = tile * TP;
    int cnt = min(TP, NPTS - p0);
    for (int r = threadIdx.x; r < cnt; r += 1024) {
        int p = p0 + r;
        uint32_t a = aux[p];
        uint32_t q = a >> 12, l = a & 4095u;
        float v = val[p];
        uint32_t pos = atomicAdd(&cur[q], 1u);
        rec[pos] = make_uint2(l, __float_as_uint(v));
    }
}

// K5: per-bucket LDS accumulate + interior TV/MSE partial + emit 6 boundary faces
__global__ void __launch_bounds__(256) accum_k(const uint2* __restrict__ rec,
                                               const uint32_t* __restrict__ base,
                                               const uint32_t* __restrict__ totals,
                                               float* __restrict__ faces,
                                               float2* __restrict__ pa) {
    __shared__ float g[4096];   // 16^3 sub-block
    int q = blockIdx.x;
    for (int c = threadIdx.x; c < 4096; c += 256) g[c] = 0.f;
    __syncthreads();
    uint32_t s0 = base[q], cnt = totals[q];
    for (uint32_t r = threadIdx.x; r < cnt; r += 256) {
        uint2 e = rec[s0 + r];
        atomicAdd(&g[e.x], __uint_as_float(e.y));
    }
    __syncthreads();
    float tv = 0.f, mse = 0.f;
    for (int l = threadIdx.x; l < 4096; l += 256) {
        float c = g[l];
        int k = l & 15, j = (l >> 4) & 15, i = l >> 8;
        if (i < 15) { float d = g[l + 256] - c; tv += fabsf(d); mse += d * d; }
        if (j < 15) { float d = g[l + 16]  - c; tv += fabsf(d); mse += d * d; }
        if (k < 15) { float d = g[l + 1]   - c; tv += fabsf(d); mse += d * d; }
    }
    // boundary faces: [q][face 0..5][256]
    {
        float* f = faces + (size_t)q * 1536;
        int t = threadIdx.x;           // 256 threads, one element per face each
        int hi = t >> 4, lo = t & 15;
        f[t]        = g[t];                        // i=0  (e = j*16+k)
        f[256 + t]  = g[3840 + t];                 // i=15
        f[512 + t]  = g[hi * 256 + lo];            // j=0  (e = i*16+k)
        f[768 + t]  = g[hi * 256 + 240 + lo];      // j=15
        f[1024 + t] = g[hi * 256 + lo * 16];       // k=0  (e = i*16+j)
        f[1280 + t] = g[hi * 256 + lo * 16 + 15];  // k=15
    }
    block_reduce2(tv, mse);
    if (threadIdx.x == 0) pa[q] = make_float2(tv, mse);
}

// K6: cross-sub-block interface diffs from face arrays
// block x = ((b*3 + axis)*7 + s)*8 + u  (batch-major so partials are contiguous per b)
__global__ void __launch_bounds__(256) boundary_k(const float* __restrict__ faces,
                                                  float2* __restrict__ pb) {
    int x = blockIdx.x;
    int u = x & 7;
    int r = x >> 3;
    int s = r % 7;
    int t = r / 7;
    int axis = t % 3;
    int b = t / 3;
    float tv = 0.f, mse = 0.f;
    for (int w = threadIdx.x; w < 2048; w += 256) {
        int v = w >> 8;
        int e = w & 255;
        int qA, qB, fA, fB;
        if (axis == 0)      { qA = (b<<9) + (s<<6) + (u<<3) + v; qB = qA + 64; fA = 256;  fB = 0;    }
        else if (axis == 1) { qA = (b<<9) + (u<<6) + (s<<3) + v; qB = qA + 8;  fA = 768;  fB = 512;  }
        else                { qA = (b<<9) + (u<<6) + (v<<3) + s; qB = qA + 1;  fA = 1280; fB = 1024; }
        float d = faces[(size_t)qB * 1536 + fB + e] - faces[(size_t)qA * 1536 + fA + e];
        tv += fabsf(d); mse += d * d;
    }
    block_reduce2(tv, mse);
    if (threadIdx.x == 0) pb[x] = make_float2(tv, mse);
}

// K7: final reduction — one block per batch, writes out directly, no atomics
__global__ void __launch_bounds__(256) final_k(const float2* __restrict__ pa,
                                               const float2* __restrict__ pb,
                                               float* __restrict__ out) {
    int b = blockIdx.x;
    float tv = 0.f, mse = 0.f;
    const float2* a = pa + (size_t)b * 512;
    for (int i = threadIdx.x; i < 512; i += 256) { float2 v = a[i]; tv += v.x; mse += v.y; }
    const float2* p = pb + (size_t)b * 168;
    for (int i = threadIdx.x; i < 168; i += 256) { float2 v = p[i]; tv += v.x; mse += v.y; }
    block_reduce2(tv, mse);
    if (threadIdx.x == 0) {
        out[b]     = tv  * (1.f / 2097152.f);   // / X^3
        out[8 + b] = mse * (1.f / 32512.f);     // / (2X^2-2X)
    }
}

extern "C" void kernel_launch(void* const* d_in, const int* in_sizes, int n_in,
                              void* d_out, int out_size, void* d_ws, size_t ws_size,
                              hipStream_t stream) {
    const int*   indices = (const int*)d_in[0];   // (B, M, 3) int32
    const float* values  = (const float*)d_in[1]; // (B, M) float32
    float*       out     = (float*)d_out;         // (2, B) float32

    // workspace layout (~61.3 MiB): aux aliases faces (aux dead once reorder_k
    // completes; faces written only by the later accum_k).
    uint32_t* hist   = (uint32_t*)d_ws;                       // NTPAD*NBQ   (4.0 MB)
    uint32_t* totals = hist + (size_t)NTPAD * NBQ;            // NBQ
    uint32_t* base   = totals + NBQ;                          // NBQ
    float2*   pa     = (float2*)(base + NBQ);                 // NBQ         (32 KB)
    float2*   pb     = pa + NBQ;                              // NBND        (10.5 KB)
    uint2*    rec    = (uint2*)(pb + NBND);                   // NPTS        (32 MB)
    float*    faces  = (float*)(rec + NPTS);                  // NBQ*1536    (25.2 MB)
    uint32_t* aux    = (uint32_t*)faces;                      // NPTS        (16 MB, aliased)

    // zero the padded hist rows [NTILE, NTPAD) so the batched scan reads zeros
    hipMemsetAsync(hist + (size_t)NTILE * NBQ, 0,
                   (size_t)(NTPAD - NTILE) * NBQ * sizeof(uint32_t), stream);

    hist_k      <<<NTILE,     1024, 0, stream>>>(indices, hist, aux);
    scan_tiles_k<<<NBQ / 256, 256,  0, stream>>>(hist, totals);
    scan_base_k <<<1,         256,  0, stream>>>(totals, base);
    reorder_k   <<<NTILE,     1024, 0, stream>>>(aux, values, hist, base, rec);
    accum_k     <<<NBQ,       256,  0, stream>>>(rec, base, totals, faces, pa);
    boundary_k  <<<NBND,      256,  0, stream>>>(faces, pb);
    final_k     <<<BATCH,     256,  0, stream>>>(pa, pb, out);
}

// Round 5
// 200.495 us; speedup vs baseline: 1.9475x; 1.0187x over previous
//
#include <hip/hip_runtime.h>
#include <stdint.h>

#define BATCH 8
#define MPTS 500000
#define NPTS (BATCH * MPTS)            // 4,000,000
#define NBQ 1024                       // buckets = 8 batches * (4*4*8) sub-blocks of 32x32x16
#define TP 8192                        // points per tile -> 8 rec/bucket avg... 8192/1024=8
#define NTILE ((NPTS + TP - 1) / TP)   // 489
#define NTPAD 512                      // padded tile rows (pad rows zeroed)
#define NIFACE 304                     // interfaces per batch: 96 + 96 + 112
#define NBND (BATCH * NIFACE)          // 2432 boundary blocks

// leaves block totals in thread 0's (tv, mse); NT = block size (multiple of 64)
template <int NT>
__device__ __forceinline__ void block_reduce2(float& tv, float& mse) {
    for (int off = 32; off > 0; off >>= 1) {
        tv  += __shfl_down(tv, off, 64);
        mse += __shfl_down(mse, off, 64);
    }
    __shared__ float stv[NT / 64], sms[NT / 64];
    int w = threadIdx.x >> 6, lane = threadIdx.x & 63;
    if (lane == 0) { stv[w] = tv; sms[w] = mse; }
    __syncthreads();
    if (threadIdx.x == 0) {
        float a = 0.f, m = 0.f;
        #pragma unroll
        for (int e = 0; e < NT / 64; ++e) { a += stv[e]; m += sms[e]; }
        tv = a; mse = m;
    }
}

// bucket q (10b) and local voxel l (14b) for grid index (i,j,k), batch b
// sub-block 32x32x16: q = (b<<7)|(i>>5<<5)|(j>>5<<3)|(k>>4); l = (i&31)*512+(j&31)*16+(k&15)
__device__ __forceinline__ uint32_t pack_aux(int b, int i, int j, int k) {
    uint32_t q = ((uint32_t)b << 7) | ((uint32_t)(i >> 5) << 5) |
                 ((uint32_t)(j >> 5) << 3) | (uint32_t)(k >> 4);
    uint32_t l = ((uint32_t)(i & 31) << 9) | ((uint32_t)(j & 31) << 4) | (uint32_t)(k & 15);
    return (q << 14) | l;
}

// K1: per-tile bucket histogram (LDS) + packed (bucket,local) aux per point
__global__ void __launch_bounds__(512) hist_k(const int* __restrict__ idx,
                                              uint32_t* __restrict__ hist,
                                              uint32_t* __restrict__ aux) {
    __shared__ uint32_t h[NBQ];
    for (int c = threadIdx.x; c < NBQ; c += 512) h[c] = 0;
    __syncthreads();
    int tile = blockIdx.x;
    int p0 = tile * TP;
    int cnt = min(TP, NPTS - p0);
    for (int r = threadIdx.x; r < cnt; r += 512) {
        int p = p0 + r;
        int b = p / MPTS;
        const int* t = idx + (size_t)p * 3;
        uint32_t a = pack_aux(b, t[0], t[1], t[2]);
        aux[p] = a;
        atomicAdd(&h[a >> 14], 1u);
    }
    __syncthreads();
    uint32_t* row = hist + (size_t)tile * NBQ;
    for (int c = threadIdx.x; c < NBQ; c += 512) row[c] = h[c];
}

// K2: per-bucket exclusive scan over tile rows (in place), 16-way load batching.
// Pad rows [NTILE, NTPAD) must be zero.
__global__ void __launch_bounds__(256) scan_tiles_k(uint32_t* __restrict__ hist,
                                                    uint32_t* __restrict__ totals) {
    int q = blockIdx.x * 256 + threadIdx.x;   // 4 blocks x 256 = 1024
    uint32_t run = 0;
    for (int t0 = 0; t0 < NTPAD; t0 += 16) {
        uint32_t v[16];
        #pragma unroll
        for (int e = 0; e < 16; ++e) v[e] = hist[(size_t)(t0 + e) * NBQ + q];
        #pragma unroll
        for (int e = 0; e < 16; ++e) {
            uint32_t hh = v[e];
            hist[(size_t)(t0 + e) * NBQ + q] = run;
            run += hh;
        }
    }
    totals[q] = run;
}

// K3: exclusive scan of 1024 totals -> base (single block, 256 thr x 4 each)
__global__ void __launch_bounds__(256) scan_base_k(const uint32_t* __restrict__ totals,
                                                   uint32_t* __restrict__ base) {
    __shared__ uint32_t ssum[256];
    uint32_t loc[4];
    int q0 = threadIdx.x * 4;
    uint32_t s = 0;
    #pragma unroll
    for (int e = 0; e < 4; ++e) { loc[e] = totals[q0 + e]; s += loc[e]; }
    ssum[threadIdx.x] = s;
    __syncthreads();
    for (int off = 1; off < 256; off <<= 1) {
        uint32_t v = 0;
        if (threadIdx.x >= off) v = ssum[threadIdx.x - off];
        __syncthreads();
        if (threadIdx.x >= off) ssum[threadIdx.x] += v;
        __syncthreads();
    }
    uint32_t run = threadIdx.x ? ssum[threadIdx.x - 1] : 0;
    #pragma unroll
    for (int e = 0; e < 4; ++e) { base[q0 + e] = run; run += loc[e]; }
}

// K4: reorder points into bucket-contiguous records (LDS cursors, no global atomics)
__global__ void __launch_bounds__(512) reorder_k(const uint32_t* __restrict__ aux,
                                                 const float* __restrict__ val,
                                                 const uint32_t* __restrict__ hist,
                                                 const uint32_t* __restrict__ base,
                                                 uint2* __restrict__ rec) {
    __shared__ uint32_t cur[NBQ];
    int tile = blockIdx.x;
    const uint32_t* offrow = hist + (size_t)tile * NBQ;
    for (int c = threadIdx.x; c < NBQ; c += 512) cur[c] = base[c] + offrow[c];
    __syncthreads();
    int p0 = tile * TP;
    int cnt = min(TP, NPTS - p0);
    for (int r = threadIdx.x; r < cnt; r += 512) {
        int p = p0 + r;
        uint32_t a = aux[p];
        float v = val[p];
        uint32_t pos = atomicAdd(&cur[a >> 14], 1u);
        rec[pos] = make_uint2(a & 16383u, __float_as_uint(v));
    }
}

// K5: per-bucket LDS accumulate (32x32x16 = 64 KB) + interior TV/MSE partial
//     + emit 6 boundary faces. 2 blocks/CU (64 KB LDS each).
__global__ void __launch_bounds__(1024) accum_k(const uint2* __restrict__ rec,
                                                const uint32_t* __restrict__ base,
                                                const uint32_t* __restrict__ totals,
                                                float* __restrict__ faces,
                                                float2* __restrict__ pa) {
    __shared__ float g[16384];   // l = il*512 + jl*16 + kl
    int q = blockIdx.x;
    for (int c = threadIdx.x; c < 16384; c += 1024) g[c] = 0.f;
    __syncthreads();
    uint32_t s0 = base[q], cnt = totals[q];
    for (uint32_t r = threadIdx.x; r < cnt; r += 1024) {
        uint2 e = rec[s0 + r];
        atomicAdd(&g[e.x], __uint_as_float(e.y));
    }
    __syncthreads();
    float tv = 0.f, mse = 0.f;
    for (int l = threadIdx.x; l < 16384; l += 1024) {
        float c = g[l];
        int kl = l & 15, jl = (l >> 4) & 31, il = l >> 9;
        if (il < 31) { float d = g[l + 512] - c; tv += fabsf(d); mse += d * d; }
        if (jl < 31) { float d = g[l + 16]  - c; tv += fabsf(d); mse += d * d; }
        if (kl < 15) { float d = g[l + 1]   - c; tv += fabsf(d); mse += d * d; }
    }
    // faces: [q][ i0:512 | i31:512 | j0:512 | j31:512 | k0:1024 | k15:1024 ]
    {
        float* f = faces + (size_t)q * 4096;
        int t = threadIdx.x;
        if (t < 512) {
            int hi = t >> 4, lo = t & 15;
            f[t]         = g[t];                     // i=0  (e = jl*16+kl)
            f[512 + t]   = g[15872 + t];             // i=31
            f[1024 + t]  = g[hi * 512 + lo];         // j=0  (e = il*16+kl)
            f[1536 + t]  = g[hi * 512 + 496 + lo];   // j=31
        }
        f[2048 + t] = g[(t >> 5) * 512 + (t & 31) * 16];        // k=0  (e = il*32+jl)
        f[3072 + t] = g[(t >> 5) * 512 + (t & 31) * 16 + 15];   // k=15
    }
    block_reduce2<1024>(tv, mse);
    if (threadIdx.x == 0) pa[q] = make_float2(tv, mse);
}

// K6: cross-sub-block interface diffs from face arrays (batch-major partials)
__global__ void __launch_bounds__(256) boundary_k(const float* __restrict__ faces,
                                                  float2* __restrict__ pb) {
    int x = blockIdx.x;
    int b = x / NIFACE;
    int r = x - b * NIFACE;
    int qA, qB, fA, fB, elems;
    if (r < 96) {                       // axis i: s in 0..2, u=bj, w=bk
        int s = r >> 5, u = (r >> 3) & 3, w = r & 7;
        qA = (b << 7) | (s << 5) | (u << 3) | w; qB = qA + 32;
        fA = 512; fB = 0; elems = 512;
    } else if (r < 192) {               // axis j: s in 0..2, u=bi, w=bk
        int r2 = r - 96;
        int s = r2 >> 5, u = (r2 >> 3) & 3, w = r2 & 7;
        qA = (b << 7) | (u << 5) | (s << 3) | w; qB = qA + 8;
        fA = 1536; fB = 1024; elems = 512;
    } else {                            // axis k: s in 0..6, u=bi, v=bj
        int r2 = r - 192;
        int s = r2 >> 4, u = (r2 >> 2) & 3, v = r2 & 3;
        qA = (b << 7) | (u << 5) | (v << 3) | s; qB = qA + 1;
        fA = 3072; fB = 2048; elems = 1024;
    }
    const float* pA = faces + (size_t)qA * 4096 + fA;
    const float* pB = faces + (size_t)qB * 4096 + fB;
    float tv = 0.f, mse = 0.f;
    for (int e = threadIdx.x; e < elems; e += 256) {
        float d = pB[e] - pA[e];
        tv += fabsf(d); mse += d * d;
    }
    block_reduce2<256>(tv, mse);
    if (threadIdx.x == 0) pb[x] = make_float2(tv, mse);
}

// K7: final reduction — one block per batch, no atomics
__global__ void __launch_bounds__(256) final_k(const float2* __restrict__ pa,
                                               const float2* __restrict__ pb,
                                               float* __restrict__ out) {
    int b = blockIdx.x;
    float tv = 0.f, mse = 0.f;
    const float2* a = pa + (size_t)b * (NBQ / BATCH);
    for (int i = threadIdx.x; i < NBQ / BATCH; i += 256) { float2 v = a[i]; tv += v.x; mse += v.y; }
    const float2* p = pb + (size_t)b * NIFACE;
    for (int i = threadIdx.x; i < NIFACE; i += 256) { float2 v = p[i]; tv += v.x; mse += v.y; }
    block_reduce2<256>(tv, mse);
    if (threadIdx.x == 0) {
        out[b]     = tv  * (1.f / 2097152.f);   // / X^3
        out[8 + b] = mse * (1.f / 32512.f);     // / (2X^2-2X)
    }
}

extern "C" void kernel_launch(void* const* d_in, const int* in_sizes, int n_in,
                              void* d_out, int out_size, void* d_ws, size_t ws_size,
                              hipStream_t stream) {
    const int*   indices = (const int*)d_in[0];   // (B, M, 3) int32
    const float* values  = (const float*)d_in[1]; // (B, M) float32
    float*       out     = (float*)d_out;         // (2, B) float32

    // workspace (~50.1 MiB): aux (16 MB) aliases faces (16 MB) — aux dead after
    // reorder_k; faces written only by the later accum_k.
    uint32_t* hist   = (uint32_t*)d_ws;                       // NTPAD*NBQ  (2.0 MB)
    uint32_t* totals = hist + (size_t)NTPAD * NBQ;            // NBQ
    uint32_t* base   = totals + NBQ;                          // NBQ
    float2*   pa     = (float2*)(base + NBQ);                 // NBQ        (8 KB)
    float2*   pb     = pa + NBQ;                              // NBND       (19 KB)
    uint2*    rec    = (uint2*)(pb + NBND);                   // NPTS       (32 MB)
    float*    faces  = (float*)(rec + NPTS);                  // NBQ*4096   (16 MB)
    uint32_t* aux    = (uint32_t*)faces;                      // NPTS       (16 MB, aliased)

    // zero padded hist rows [NTILE, NTPAD) so the batched scan reads zeros
    hipMemsetAsync(hist + (size_t)NTILE * NBQ, 0,
                   (size_t)(NTPAD - NTILE) * NBQ * sizeof(uint32_t), stream);

    hist_k      <<<NTILE,     512,  0, stream>>>(indices, hist, aux);
    scan_tiles_k<<<NBQ / 256, 256,  0, stream>>>(hist, totals);
    scan_base_k <<<1,         256,  0, stream>>>(totals, base);
    reorder_k   <<<NTILE,     512,  0, stream>>>(aux, values, hist, base, rec);
    accum_k     <<<NBQ,       1024, 0, stream>>>(rec, base, totals, faces, pa);
    boundary_k  <<<NBND,      256,  0, stream>>>(faces, pb);
    final_k     <<<BATCH,     256,  0, stream>>>(pa, pb, out);
}

// Round 6
// 173.146 us; speedup vs baseline: 2.2551x; 1.1580x over previous
//
#include <hip/hip_runtime.h>
#include <stdint.h>

#define BATCH 8
#define MPTS 500000
#define NPTS (BATCH * MPTS)            // 4,000,000
#define NBQ 1024                       // buckets = 8 batches * (4*4*8) sub-blocks of 32x32x16
#define TP 8192                        // points per tile
#define NTILE ((NPTS + TP - 1) / TP)   // 489
#define NTPAD 512                      // padded tile rows (pad rows zeroed)
#define NIFACE 304                     // interfaces per batch: 96 + 96 + 112
#define NBND (BATCH * NIFACE)          // 2432 boundary blocks

// leaves block totals in thread 0's (tv, mse); NT = block size (multiple of 64)
template <int NT>
__device__ __forceinline__ void block_reduce2(float& tv, float& mse) {
    for (int off = 32; off > 0; off >>= 1) {
        tv  += __shfl_down(tv, off, 64);
        mse += __shfl_down(mse, off, 64);
    }
    __shared__ float stv[NT / 64], sms[NT / 64];
    int w = threadIdx.x >> 6, lane = threadIdx.x & 63;
    if (lane == 0) { stv[w] = tv; sms[w] = mse; }
    __syncthreads();
    if (threadIdx.x == 0) {
        float a = 0.f, m = 0.f;
        #pragma unroll
        for (int e = 0; e < NT / 64; ++e) { a += stv[e]; m += sms[e]; }
        tv = a; mse = m;
    }
}

// aux = (q:10 | l:14); sub-block 32x32x16
__device__ __forceinline__ uint32_t pack_aux(int b, int i, int j, int k) {
    uint32_t q = ((uint32_t)b << 7) | ((uint32_t)(i >> 5) << 5) |
                 ((uint32_t)(j >> 5) << 3) | (uint32_t)(k >> 4);
    uint32_t l = ((uint32_t)(i & 31) << 9) | ((uint32_t)(j & 31) << 4) | (uint32_t)(k & 15);
    return (q << 14) | l;
}

// K1: per-tile bucket histogram (LDS) + packed aux per point. int4-vectorized:
// 4 points = 3 int4 loads; 500000 % 4 == 0 so a group never straddles a batch.
__global__ void __launch_bounds__(1024) hist_k(const int* __restrict__ idx,
                                               uint32_t* __restrict__ hist,
                                               uint32_t* __restrict__ aux) {
    __shared__ uint32_t h[NBQ];
    if (threadIdx.x < NBQ) h[threadIdx.x] = 0;
    __syncthreads();
    int tile = blockIdx.x;
    int p0 = tile * TP;
    int ng = min(TP, NPTS - p0) >> 2;   // groups of 4 (cnt always multiple of 4)
    for (int g = threadIdx.x; g < ng; g += 1024) {
        int p = p0 + g * 4;
        const int4* ip = (const int4*)(idx + (size_t)p * 3);
        int4 A = ip[0], B = ip[1], C = ip[2];
        int b = p / MPTS;
        uint32_t a0 = pack_aux(b, A.x, A.y, A.z);
        uint32_t a1 = pack_aux(b, A.w, B.x, B.y);
        uint32_t a2 = pack_aux(b, B.z, B.w, C.x);
        uint32_t a3 = pack_aux(b, C.y, C.z, C.w);
        *(uint4*)(aux + p) = make_uint4(a0, a1, a2, a3);
        atomicAdd(&h[a0 >> 14], 1u);
        atomicAdd(&h[a1 >> 14], 1u);
        atomicAdd(&h[a2 >> 14], 1u);
        atomicAdd(&h[a3 >> 14], 1u);
    }
    __syncthreads();
    if (threadIdx.x < NBQ) hist[(size_t)tile * NBQ + threadIdx.x] = h[threadIdx.x];
}

// K2: per-bucket exclusive scan over tile rows (in place), 16-way load batching.
__global__ void __launch_bounds__(256) scan_tiles_k(uint32_t* __restrict__ hist,
                                                    uint32_t* __restrict__ totals) {
    int q = blockIdx.x * 256 + threadIdx.x;   // 4 blocks x 256 = 1024
    uint32_t run = 0;
    for (int t0 = 0; t0 < NTPAD; t0 += 16) {
        uint32_t v[16];
        #pragma unroll
        for (int e = 0; e < 16; ++e) v[e] = hist[(size_t)(t0 + e) * NBQ + q];
        #pragma unroll
        for (int e = 0; e < 16; ++e) {
            uint32_t hh = v[e];
            hist[(size_t)(t0 + e) * NBQ + q] = run;
            run += hh;
        }
    }
    totals[q] = run;
}

// K3: exclusive scan of 1024 totals -> base (single block)
__global__ void __launch_bounds__(256) scan_base_k(const uint32_t* __restrict__ totals,
                                                   uint32_t* __restrict__ base) {
    __shared__ uint32_t ssum[256];
    uint32_t loc[4];
    int q0 = threadIdx.x * 4;
    uint32_t s = 0;
    #pragma unroll
    for (int e = 0; e < 4; ++e) { loc[e] = totals[q0 + e]; s += loc[e]; }
    ssum[threadIdx.x] = s;
    __syncthreads();
    for (int off = 1; off < 256; off <<= 1) {
        uint32_t v = 0;
        if (threadIdx.x >= off) v = ssum[threadIdx.x - off];
        __syncthreads();
        if (threadIdx.x >= off) ssum[threadIdx.x] += v;
        __syncthreads();
    }
    uint32_t run = threadIdx.x ? ssum[threadIdx.x - 1] : 0;
    #pragma unroll
    for (int e = 0; e < 4; ++e) { base[q0 + e] = run; run += loc[e]; }
}

// K4: block-local counting sort in LDS, then near-coalesced writeout of 4-byte
// records rec = (val_top18 << 14) | local14. No global atomics.
__global__ void __launch_bounds__(1024) reorder_k(const uint32_t* __restrict__ aux,
                                                  const float* __restrict__ val,
                                                  const uint32_t* __restrict__ hist,
                                                  const uint32_t* __restrict__ base,
                                                  uint32_t* __restrict__ rec) {
    __shared__ uint32_t h[NBQ];     // counts -> cursors (local start offsets)
    __shared__ uint32_t sc[NBQ];    // scan buffer
    __shared__ uint32_t gb[NBQ];    // gb[q] = base[q] + offrow[q] - lstart[q]
    __shared__ uint16_t sq[TP];     // bucket of sorted slot
    __shared__ uint32_t srt[TP];    // sorted packed records
    int tile = blockIdx.x;
    int p0 = tile * TP;
    int cnt = min(TP, NPTS - p0);
    if (threadIdx.x < NBQ) h[threadIdx.x] = 0;
    __syncthreads();
    // phase 1: local histogram (aux re-read in phase 3 hits L2)
    for (int r = threadIdx.x; r < cnt; r += 1024)
        atomicAdd(&h[aux[p0 + r] >> 14], 1u);
    __syncthreads();
    // phase 2: block exclusive scan of 1024 counts (blockDim == NBQ)
    int q = threadIdx.x;
    uint32_t cq = h[q];
    sc[q] = cq;
    __syncthreads();
    for (int off = 1; off < NBQ; off <<= 1) {
        uint32_t v = (q >= off) ? sc[q - off] : 0u;
        __syncthreads();
        sc[q] += v;
        __syncthreads();
    }
    uint32_t lstart = sc[q] - cq;
    gb[q] = base[q] + hist[(size_t)tile * NBQ + q] - lstart;
    h[q] = lstart;          // reuse as placement cursor
    __syncthreads();
    // phase 3: place into LDS sorted order, encode value to top-18 bits
    for (int r = threadIdx.x; r < cnt; r += 1024) {
        uint32_t a = aux[p0 + r];
        float f = val[p0 + r];
        uint32_t u = (__float_as_uint(f) + 0x2000u) & 0xFFFFC000u;  // rne-ish trunc
        uint32_t qq = a >> 14;
        uint32_t pos = atomicAdd(&h[qq], 1u);
        srt[pos] = u | (a & 16383u);
        sq[pos]  = (uint16_t)qq;
    }
    __syncthreads();
    // phase 4: writeout — consecutive t -> consecutive dst within bucket runs
    for (int t = threadIdx.x; t < cnt; t += 1024) {
        uint32_t qq = sq[t];
        rec[gb[qq] + t] = srt[t];
    }
}

// K5: per-bucket LDS accumulate (32x32x16 = 64 KB) + interior TV/MSE partial
//     + emit 6 boundary faces.
__global__ void __launch_bounds__(1024) accum_k(const uint32_t* __restrict__ rec,
                                                const uint32_t* __restrict__ base,
                                                const uint32_t* __restrict__ totals,
                                                float* __restrict__ faces,
                                                float2* __restrict__ pa) {
    __shared__ float g[16384];   // l = il*512 + jl*16 + kl
    int q = blockIdx.x;
    for (int c = threadIdx.x; c < 16384; c += 1024) g[c] = 0.f;
    __syncthreads();
    uint32_t s0 = base[q], cnt = totals[q];
    for (uint32_t r = threadIdx.x; r < cnt; r += 1024) {
        uint32_t e = rec[s0 + r];
        atomicAdd(&g[e & 16383u], __uint_as_float(e & 0xFFFFC000u));
    }
    __syncthreads();
    float tv = 0.f, mse = 0.f;
    for (int l = threadIdx.x; l < 16384; l += 1024) {
        float c = g[l];
        int kl = l & 15, jl = (l >> 4) & 31, il = l >> 9;
        if (il < 31) { float d = g[l + 512] - c; tv += fabsf(d); mse += d * d; }
        if (jl < 31) { float d = g[l + 16]  - c; tv += fabsf(d); mse += d * d; }
        if (kl < 15) { float d = g[l + 1]   - c; tv += fabsf(d); mse += d * d; }
    }
    // faces: [q][ i0:512 | i31:512 | j0:512 | j31:512 | k0:1024 | k15:1024 ]
    {
        float* f = faces + (size_t)q * 4096;
        int t = threadIdx.x;
        if (t < 512) {
            int hi = t >> 4, lo = t & 15;
            f[t]         = g[t];                     // i=0  (e = jl*16+kl)
            f[512 + t]   = g[15872 + t];             // i=31
            f[1024 + t]  = g[hi * 512 + lo];         // j=0  (e = il*16+kl)
            f[1536 + t]  = g[hi * 512 + 496 + lo];   // j=31
        }
        f[2048 + t] = g[(t >> 5) * 512 + (t & 31) * 16];        // k=0  (e = il*32+jl)
        f[3072 + t] = g[(t >> 5) * 512 + (t & 31) * 16 + 15];   // k=15
    }
    block_reduce2<1024>(tv, mse);
    if (threadIdx.x == 0) pa[q] = make_float2(tv, mse);
}

// K6: cross-sub-block interface diffs from face arrays (batch-major partials)
__global__ void __launch_bounds__(256) boundary_k(const float* __restrict__ faces,
                                                  float2* __restrict__ pb) {
    int x = blockIdx.x;
    int b = x / NIFACE;
    int r = x - b * NIFACE;
    int qA, qB, fA, fB, elems;
    if (r < 96) {                       // axis i
        int s = r >> 5, u = (r >> 3) & 3, w = r & 7;
        qA = (b << 7) | (s << 5) | (u << 3) | w; qB = qA + 32;
        fA = 512; fB = 0; elems = 512;
    } else if (r < 192) {               // axis j
        int r2 = r - 96;
        int s = r2 >> 5, u = (r2 >> 3) & 3, w = r2 & 7;
        qA = (b << 7) | (u << 5) | (s << 3) | w; qB = qA + 8;
        fA = 1536; fB = 1024; elems = 512;
    } else {                            // axis k
        int r2 = r - 192;
        int s = r2 >> 4, u = (r2 >> 2) & 3, v = r2 & 3;
        qA = (b << 7) | (u << 5) | (v << 3) | s; qB = qA + 1;
        fA = 3072; fB = 2048; elems = 1024;
    }
    const float* pA = faces + (size_t)qA * 4096 + fA;
    const float* pB = faces + (size_t)qB * 4096 + fB;
    float tv = 0.f, mse = 0.f;
    for (int e = threadIdx.x; e < elems; e += 256) {
        float d = pB[e] - pA[e];
        tv += fabsf(d); mse += d * d;
    }
    block_reduce2<256>(tv, mse);
    if (threadIdx.x == 0) pb[x] = make_float2(tv, mse);
}

// K7: final reduction — one block per batch, no atomics
__global__ void __launch_bounds__(256) final_k(const float2* __restrict__ pa,
                                               const float2* __restrict__ pb,
                                               float* __restrict__ out) {
    int b = blockIdx.x;
    float tv = 0.f, mse = 0.f;
    const float2* a = pa + (size_t)b * (NBQ / BATCH);
    for (int i = threadIdx.x; i < NBQ / BATCH; i += 256) { float2 v = a[i]; tv += v.x; mse += v.y; }
    const float2* p = pb + (size_t)b * NIFACE;
    for (int i = threadIdx.x; i < NIFACE; i += 256) { float2 v = p[i]; tv += v.x; mse += v.y; }
    block_reduce2<256>(tv, mse);
    if (threadIdx.x == 0) {
        out[b]     = tv  * (1.f / 2097152.f);   // / X^3
        out[8 + b] = mse * (1.f / 32512.f);     // / (2X^2-2X)
    }
}

extern "C" void kernel_launch(void* const* d_in, const int* in_sizes, int n_in,
                              void* d_out, int out_size, void* d_ws, size_t ws_size,
                              hipStream_t stream) {
    const int*   indices = (const int*)d_in[0];   // (B, M, 3) int32
    const float* values  = (const float*)d_in[1]; // (B, M) float32
    float*       out     = (float*)d_out;         // (2, B) float32

    // workspace (~34 MiB): aux (16 MB) aliases faces (16 MB) — aux dead after
    // reorder_k; faces written only by the later accum_k.
    uint32_t* hist   = (uint32_t*)d_ws;                       // NTPAD*NBQ  (2.0 MB)
    uint32_t* totals = hist + (size_t)NTPAD * NBQ;            // NBQ
    uint32_t* base   = totals + NBQ;                          // NBQ
    float2*   pa     = (float2*)(base + NBQ);                 // NBQ        (8 KB)
    float2*   pb     = pa + NBQ;                              // NBND       (19 KB)
    uint32_t* rec    = (uint32_t*)(pb + NBND);                // NPTS       (16 MB)
    float*    faces  = (float*)(rec + NPTS);                  // NBQ*4096   (16 MB)
    uint32_t* aux    = (uint32_t*)faces;                      // NPTS       (16 MB, aliased)

    // zero padded hist rows [NTILE, NTPAD) so the batched scan reads zeros
    hipMemsetAsync(hist + (size_t)NTILE * NBQ, 0,
                   (size_t)(NTPAD - NTILE) * NBQ * sizeof(uint32_t), stream);

    hist_k      <<<NTILE,     1024, 0, stream>>>(indices, hist, aux);
    scan_tiles_k<<<NBQ / 256, 256,  0, stream>>>(hist, totals);
    scan_base_k <<<1,         256,  0, stream>>>(totals, base);
    reorder_k   <<<NTILE,     1024, 0, stream>>>(aux, values, hist, base, rec);
    accum_k     <<<NBQ,       1024, 0, stream>>>(rec, base, totals, faces, pa);
    boundary_k  <<<NBND,      256,  0, stream>>>(faces, pb);
    final_k     <<<BATCH,     256,  0, stream>>>(pa, pb, out);
}

// Round 7
// 166.053 us; speedup vs baseline: 2.3514x; 1.0427x over previous
//
#include <hip/hip_runtime.h>
#include <stdint.h>

#define BATCH 8
#define MPTS 500000
#define NPTS (BATCH * MPTS)            // 4,000,000
#define NBQ 1024                       // buckets = 8 batches * (4*4*8) sub-blocks of 32x32x16
#define TP 8192                        // points per tile
#define NTILE ((NPTS + TP - 1) / TP)   // 489
#define NIFACE 304                     // interfaces per batch: 96 + 96 + 112
#define NBND (BATCH * NIFACE)          // 2432 boundary blocks

template <int NT>
__device__ __forceinline__ void block_reduce2(float& tv, float& mse) {
    for (int off = 32; off > 0; off >>= 1) {
        tv  += __shfl_down(tv, off, 64);
        mse += __shfl_down(mse, off, 64);
    }
    __shared__ float stv[NT / 64], sms[NT / 64];
    int w = threadIdx.x >> 6, lane = threadIdx.x & 63;
    if (lane == 0) { stv[w] = tv; sms[w] = mse; }
    __syncthreads();
    if (threadIdx.x == 0) {
        float a = 0.f, m = 0.f;
        #pragma unroll
        for (int e = 0; e < NT / 64; ++e) { a += stv[e]; m += sms[e]; }
        tv = a; mse = m;
    }
}

// aux = (q:10 | l:14); sub-block 32x32x16. aux < 2^24 so 0xFFFFFFFF is a safe sentinel.
__device__ __forceinline__ uint32_t pack_aux(int b, int i, int j, int k) {
    uint32_t q = ((uint32_t)b << 7) | ((uint32_t)(i >> 5) << 5) |
                 ((uint32_t)(j >> 5) << 3) | (uint32_t)(k >> 4);
    uint32_t l = ((uint32_t)(i & 31) << 9) | ((uint32_t)(j & 31) << 4) | (uint32_t)(k & 15);
    return (q << 14) | l;
}

// K1: per-tile bucket histogram (LDS) + packed aux per point, int4-vectorized.
__global__ void __launch_bounds__(1024) hist_k(const int* __restrict__ idx,
                                               uint32_t* __restrict__ hist,
                                               uint32_t* __restrict__ aux) {
    __shared__ uint32_t h[NBQ];
    h[threadIdx.x] = 0;
    __syncthreads();
    int tile = blockIdx.x;
    int p0 = tile * TP;
    int ng = min(TP, NPTS - p0) >> 2;   // groups of 4 (cnt always multiple of 4)
    for (int g = threadIdx.x; g < ng; g += 1024) {
        int p = p0 + g * 4;
        const int4* ip = (const int4*)(idx + (size_t)p * 3);
        int4 A = ip[0], B = ip[1], C = ip[2];
        int b = p / MPTS;
        uint32_t a0 = pack_aux(b, A.x, A.y, A.z);
        uint32_t a1 = pack_aux(b, A.w, B.x, B.y);
        uint32_t a2 = pack_aux(b, B.z, B.w, C.x);
        uint32_t a3 = pack_aux(b, C.y, C.z, C.w);
        *(uint4*)(aux + p) = make_uint4(a0, a1, a2, a3);
        atomicAdd(&h[a0 >> 14], 1u);
        atomicAdd(&h[a1 >> 14], 1u);
        atomicAdd(&h[a2 >> 14], 1u);
        atomicAdd(&h[a3 >> 14], 1u);
    }
    __syncthreads();
    hist[(size_t)tile * NBQ + threadIdx.x] = h[threadIdx.x];
}

// K2: per-bucket exclusive scan over tile rows (in place), 16-way batched with
// tail guards (no padding, no memset). 16 blocks x 64 threads.
__global__ void __launch_bounds__(64) scan_tiles_k(uint32_t* __restrict__ hist,
                                                   uint32_t* __restrict__ totals) {
    int q = blockIdx.x * 64 + threadIdx.x;   // 16 * 64 = 1024
    uint32_t run = 0;
    for (int t0 = 0; t0 < NTILE; t0 += 16) {
        uint32_t vv[16];
        #pragma unroll
        for (int e = 0; e < 16; ++e) {
            int t = t0 + e;
            vv[e] = (t < NTILE) ? hist[(size_t)t * NBQ + q] : 0u;
        }
        #pragma unroll
        for (int e = 0; e < 16; ++e) {
            int t = t0 + e;
            if (t < NTILE) hist[(size_t)t * NBQ + q] = run;
            run += vv[e];
        }
    }
    totals[q] = run;
}

// K3: exclusive scan of 1024 totals -> base (single block)
__global__ void __launch_bounds__(256) scan_base_k(const uint32_t* __restrict__ totals,
                                                   uint32_t* __restrict__ base) {
    __shared__ uint32_t ssum[256];
    uint32_t loc[4];
    int q0 = threadIdx.x * 4;
    uint32_t s = 0;
    #pragma unroll
    for (int e = 0; e < 4; ++e) { loc[e] = totals[q0 + e]; s += loc[e]; }
    ssum[threadIdx.x] = s;
    __syncthreads();
    for (int off = 1; off < 256; off <<= 1) {
        uint32_t v = 0;
        if (threadIdx.x >= off) v = ssum[threadIdx.x - off];
        __syncthreads();
        if (threadIdx.x >= off) ssum[threadIdx.x] += v;
        __syncthreads();
    }
    uint32_t run = threadIdx.x ? ssum[threadIdx.x - 1] : 0;
    #pragma unroll
    for (int e = 0; e < 4; ++e) { base[q0 + e] = run; run += loc[e]; }
}

// K4: block-local counting sort; aux+val held in registers across phases;
// shuffle-hierarchical block scan (2 barriers); near-coalesced 4B record writeout.
__global__ void __launch_bounds__(1024, 8) reorder_k(const uint32_t* __restrict__ aux,
                                                     const float* __restrict__ val,
                                                     const uint32_t* __restrict__ hist,
                                                     const uint32_t* __restrict__ base,
                                                     uint32_t* __restrict__ rec) {
    __shared__ uint32_t h[NBQ];     // counts -> placement cursors
    __shared__ uint32_t gb[NBQ];    // gb[q] = base[q] + offrow[q] - lstart[q]
    __shared__ uint32_t wtot[16];
    __shared__ uint16_t sq[TP];     // bucket of sorted slot
    __shared__ uint32_t srt[TP];    // sorted packed records
    int tile = blockIdx.x;
    int p0 = tile * TP;
    int cnt = min(TP, NPTS - p0);
    h[threadIdx.x] = 0;
    __syncthreads();
    // phase 1: load points into registers + LDS histogram
    uint32_t a[8]; float v[8];
    #pragma unroll
    for (int e = 0; e < 8; ++e) {
        int r = threadIdx.x + e * 1024;
        if (r < cnt) {
            a[e] = aux[p0 + r];
            v[e] = val[p0 + r];
            atomicAdd(&h[a[e] >> 14], 1u);
        } else a[e] = 0xFFFFFFFFu;
    }
    __syncthreads();
    // phase 2: block exclusive scan of 1024 counts (wave shuffles, 2 barriers)
    int q = threadIdx.x, lane = q & 63, wave = q >> 6;
    uint32_t cq = h[q];
    uint32_t inc = cq;
    #pragma unroll
    for (int off = 1; off < 64; off <<= 1) {
        uint32_t n = __shfl_up(inc, off, 64);
        if (lane >= off) inc += n;
    }
    if (lane == 63) wtot[wave] = inc;
    __syncthreads();
    if (q < 16) {
        uint32_t w = wtot[q];
        #pragma unroll
        for (int off = 1; off < 16; off <<= 1) {
            uint32_t n = __shfl_up(w, off, 16);
            if (q >= off) w += n;
        }
        wtot[q] = w;   // inclusive wave totals
    }
    __syncthreads();
    uint32_t lstart = (wave ? wtot[wave - 1] : 0u) + inc - cq;
    gb[q] = base[q] + hist[(size_t)tile * NBQ + q] - lstart;
    h[q] = lstart;          // placement cursor
    __syncthreads();
    // phase 3: place into LDS sorted order; value encoded to top-18 bits
    #pragma unroll
    for (int e = 0; e < 8; ++e) {
        if (a[e] != 0xFFFFFFFFu) {
            uint32_t qq = a[e] >> 14;
            uint32_t u = (__float_as_uint(v[e]) + 0x2000u) & 0xFFFFC000u;
            uint32_t pos = atomicAdd(&h[qq], 1u);
            srt[pos] = u | (a[e] & 16383u);
            sq[pos]  = (uint16_t)qq;
        }
    }
    __syncthreads();
    // phase 4: writeout — consecutive t -> consecutive dst within bucket runs
    for (int t = threadIdx.x; t < cnt; t += 1024)
        rec[gb[sq[t]] + t] = srt[t];
}

// K5: per-bucket LDS accumulate (32x32x16 = 64 KB) + k-line vectorized stencil
//     + emit 6 boundary faces.
__global__ void __launch_bounds__(1024, 8) accum_k(const uint32_t* __restrict__ rec,
                                                   const uint32_t* __restrict__ base,
                                                   const uint32_t* __restrict__ totals,
                                                   float* __restrict__ faces,
                                                   float2* __restrict__ pa) {
    __shared__ float g[16384];   // l = il*512 + jl*16 + kl
    int q = blockIdx.x;
    for (int c = threadIdx.x; c < 16384; c += 1024) g[c] = 0.f;
    __syncthreads();
    uint32_t s0 = base[q], cnt = totals[q];
    for (uint32_t r = threadIdx.x; r < cnt; r += 1024) {
        uint32_t e = rec[s0 + r];
        atomicAdd(&g[e & 16383u], __uint_as_float(e & 0xFFFFC000u));
    }
    __syncthreads();
    // stencil: one k-line (16 voxels) per thread, processed in two 8-halves.
    // Own line + j-neighbor + i-neighbor via ds_read_b128.
    float tv = 0.f, mse = 0.f;
    {
        int il = threadIdx.x >> 5, jl = threadIdx.x & 31;
        int lb = il * 512 + jl * 16;
        bool jin = jl < 31, iin = il < 31;
        #pragma unroll
        for (int half = 0; half < 2; ++half) {
            int k0 = half * 8;
            float own[8], jn[8], inb[8];
            *(float4*)&own[0] = *(const float4*)&g[lb + k0];
            *(float4*)&own[4] = *(const float4*)&g[lb + k0 + 4];
            // k-diffs: 7 internal per half + the 7->8 seam on half 0
            #pragma unroll
            for (int k = 0; k < 7; ++k) {
                float d = own[k + 1] - own[k]; tv += fabsf(d); mse += d * d;
            }
            if (half == 0) {
                float d = g[lb + 8] - own[7]; tv += fabsf(d); mse += d * d;
            }
            if (jin) {
                *(float4*)&jn[0] = *(const float4*)&g[lb + 16 + k0];
                *(float4*)&jn[4] = *(const float4*)&g[lb + 16 + k0 + 4];
                #pragma unroll
                for (int k = 0; k < 8; ++k) {
                    float d = jn[k] - own[k]; tv += fabsf(d); mse += d * d;
                }
            }
            if (iin) {
                *(float4*)&inb[0] = *(const float4*)&g[lb + 512 + k0];
                *(float4*)&inb[4] = *(const float4*)&g[lb + 512 + k0 + 4];
                #pragma unroll
                for (int k = 0; k < 8; ++k) {
                    float d = inb[k] - own[k]; tv += fabsf(d); mse += d * d;
                }
            }
        }
    }
    // faces: [q][ i0:512 | i31:512 | j0:512 | j31:512 | k0:1024 | k15:1024 ]
    {
        float* f = faces + (size_t)q * 4096;
        int t = threadIdx.x;
        if (t < 512) {
            int hi = t >> 4, lo = t & 15;
            f[t]         = g[t];                     // i=0  (e = jl*16+kl)
            f[512 + t]   = g[15872 + t];             // i=31
            f[1024 + t]  = g[hi * 512 + lo];         // j=0  (e = il*16+kl)
            f[1536 + t]  = g[hi * 512 + 496 + lo];   // j=31
        }
        f[2048 + t] = g[(t >> 5) * 512 + (t & 31) * 16];        // k=0  (e = il*32+jl)
        f[3072 + t] = g[(t >> 5) * 512 + (t & 31) * 16 + 15];   // k=15
    }
    block_reduce2<1024>(tv, mse);
    if (threadIdx.x == 0) pa[q] = make_float2(tv, mse);
}

// K6: cross-sub-block interface diffs from face arrays (batch-major partials)
__global__ void __launch_bounds__(256) boundary_k(const float* __restrict__ faces,
                                                  float2* __restrict__ pb) {
    int x = blockIdx.x;
    int b = x / NIFACE;
    int r = x - b * NIFACE;
    int qA, qB, fA, fB, elems;
    if (r < 96) {                       // axis i
        int s = r >> 5, u = (r >> 3) & 3, w = r & 7;
        qA = (b << 7) | (s << 5) | (u << 3) | w; qB = qA + 32;
        fA = 512; fB = 0; elems = 512;
    } else if (r < 192) {               // axis j
        int r2 = r - 96;
        int s = r2 >> 5, u = (r2 >> 3) & 3, w = r2 & 7;
        qA = (b << 7) | (u << 5) | (s << 3) | w; qB = qA + 8;
        fA = 1536; fB = 1024; elems = 512;
    } else {                            // axis k
        int r2 = r - 192;
        int s = r2 >> 4, u = (r2 >> 2) & 3, v = r2 & 3;
        qA = (b << 7) | (u << 5) | (v << 3) | s; qB = qA + 1;
        fA = 3072; fB = 2048; elems = 1024;
    }
    const float* pA = faces + (size_t)qA * 4096 + fA;
    const float* pB = faces + (size_t)qB * 4096 + fB;
    float tv = 0.f, mse = 0.f;
    for (int e = threadIdx.x; e < elems; e += 256) {
        float d = pB[e] - pA[e];
        tv += fabsf(d); mse += d * d;
    }
    block_reduce2<256>(tv, mse);
    if (threadIdx.x == 0) pb[x] = make_float2(tv, mse);
}

// K7: final reduction — one block per batch, no atomics
__global__ void __launch_bounds__(256) final_k(const float2* __restrict__ pa,
                                               const float2* __restrict__ pb,
                                               float* __restrict__ out) {
    int b = blockIdx.x;
    float tv = 0.f, mse = 0.f;
    const float2* a = pa + (size_t)b * (NBQ / BATCH);
    for (int i = threadIdx.x; i < NBQ / BATCH; i += 256) { float2 v = a[i]; tv += v.x; mse += v.y; }
    const float2* p = pb + (size_t)b * NIFACE;
    for (int i = threadIdx.x; i < NIFACE; i += 256) { float2 v = p[i]; tv += v.x; mse += v.y; }
    block_reduce2<256>(tv, mse);
    if (threadIdx.x == 0) {
        out[b]     = tv  * (1.f / 2097152.f);   // / X^3
        out[8 + b] = mse * (1.f / 32512.f);     // / (2X^2-2X)
    }
}

extern "C" void kernel_launch(void* const* d_in, const int* in_sizes, int n_in,
                              void* d_out, int out_size, void* d_ws, size_t ws_size,
                              hipStream_t stream) {
    const int*   indices = (const int*)d_in[0];   // (B, M, 3) int32
    const float* values  = (const float*)d_in[1]; // (B, M) float32
    float*       out     = (float*)d_out;         // (2, B) float32

    // workspace (~34 MiB): aux (16 MB) aliases faces (16 MB) — aux dead after
    // reorder_k; faces written only by the later accum_k.
    uint32_t* hist   = (uint32_t*)d_ws;                       // NTILE*NBQ  (2.0 MB)
    uint32_t* totals = hist + (size_t)NTILE * NBQ;            // NBQ
    uint32_t* base   = totals + NBQ;                          // NBQ
    float2*   pa     = (float2*)(base + NBQ);                 // NBQ        (8 KB)
    float2*   pb     = pa + NBQ;                              // NBND       (19 KB)
    uint32_t* rec    = (uint32_t*)(pb + NBND);                // NPTS       (16 MB)
    float*    faces  = (float*)(rec + NPTS);                  // NBQ*4096   (16 MB)
    uint32_t* aux    = (uint32_t*)faces;                      // NPTS       (16 MB, aliased)

    hist_k      <<<NTILE, 1024, 0, stream>>>(indices, hist, aux);
    scan_tiles_k<<<16,    64,   0, stream>>>(hist, totals);
    scan_base_k <<<1,     256,  0, stream>>>(totals, base);
    reorder_k   <<<NTILE, 1024, 0, stream>>>(aux, values, hist, base, rec);
    accum_k     <<<NBQ,   1024, 0, stream>>>(rec, base, totals, faces, pa);
    boundary_k  <<<NBND,  256,  0, stream>>>(faces, pb);
    final_k     <<<BATCH, 256,  0, stream>>>(pa, pb, out);
}

// Round 8
// 158.259 us; speedup vs baseline: 2.4672x; 1.0492x over previous
//
#include <hip/hip_runtime.h>
#include <stdint.h>

#define BATCH 8
#define MPTS 500000
#define NPTS (BATCH * MPTS)            // 4,000,000
#define NBQ 1024                       // buckets = 8 batches * (4*4*8) sub-blocks of 32x32x16
#define TP 8192                        // points per tile
#define NTILE ((NPTS + TP - 1) / TP)   // 489
#define NIFACE 304                     // interfaces per batch: 96 + 96 + 112
#define NBND (BATCH * NIFACE)          // 2432 boundary blocks

template <int NT>
__device__ __forceinline__ void block_reduce2(float& tv, float& mse) {
    for (int off = 32; off > 0; off >>= 1) {
        tv  += __shfl_down(tv, off, 64);
        mse += __shfl_down(mse, off, 64);
    }
    __shared__ float stv[NT / 64], sms[NT / 64];
    int w = threadIdx.x >> 6, lane = threadIdx.x & 63;
    if (lane == 0) { stv[w] = tv; sms[w] = mse; }
    __syncthreads();
    if (threadIdx.x == 0) {
        float a = 0.f, m = 0.f;
        #pragma unroll
        for (int e = 0; e < NT / 64; ++e) { a += stv[e]; m += sms[e]; }
        tv = a; mse = m;
    }
}

// aux = (q:10 | l:14); sub-block 32x32x16. aux < 2^24 so 0xFFFFFFFF is a safe sentinel.
__device__ __forceinline__ uint32_t pack_aux(int b, int i, int j, int k) {
    uint32_t q = ((uint32_t)b << 7) | ((uint32_t)(i >> 5) << 5) |
                 ((uint32_t)(j >> 5) << 3) | (uint32_t)(k >> 4);
    uint32_t l = ((uint32_t)(i & 31) << 9) | ((uint32_t)(j & 31) << 4) | (uint32_t)(k & 15);
    return (q << 14) | l;
}

// LDS bank swizzle for accum_k grid: line s = il*32+jl holds 16 dwords; the
// group-of-4 index is XORed with (s>>1) so wave-wide b128 reads touch all 32
// banks (keyed off s>>1, independent of the bank-polarity bit s&1).
__device__ __forceinline__ int gaddr(int s, int kl) {
    return s * 16 + (kl & 3) + ((((kl >> 2) ^ (s >> 1)) & 3) << 2);
}
// physical dword offset (0..15) of logical group c in line s
__device__ __forceinline__ int goff(int s, int c) {
    return ((c ^ (s >> 1)) & 3) << 2;
}

// K1: per-tile bucket histogram (LDS) + packed aux per point, int4-vectorized.
__global__ void __launch_bounds__(1024) hist_k(const int* __restrict__ idx,
                                               uint32_t* __restrict__ hist,
                                               uint32_t* __restrict__ aux) {
    __shared__ uint32_t h[NBQ];
    h[threadIdx.x] = 0;
    __syncthreads();
    int tile = blockIdx.x;
    int p0 = tile * TP;
    int ng = min(TP, NPTS - p0) >> 2;   // groups of 4 (cnt always multiple of 4)
    for (int g = threadIdx.x; g < ng; g += 1024) {
        int p = p0 + g * 4;
        const int4* ip = (const int4*)(idx + (size_t)p * 3);
        int4 A = ip[0], B = ip[1], C = ip[2];
        int b = p / MPTS;
        uint32_t a0 = pack_aux(b, A.x, A.y, A.z);
        uint32_t a1 = pack_aux(b, A.w, B.x, B.y);
        uint32_t a2 = pack_aux(b, B.z, B.w, C.x);
        uint32_t a3 = pack_aux(b, C.y, C.z, C.w);
        *(uint4*)(aux + p) = make_uint4(a0, a1, a2, a3);
        atomicAdd(&h[a0 >> 14], 1u);
        atomicAdd(&h[a1 >> 14], 1u);
        atomicAdd(&h[a2 >> 14], 1u);
        atomicAdd(&h[a3 >> 14], 1u);
    }
    __syncthreads();
    hist[(size_t)tile * NBQ + threadIdx.x] = h[threadIdx.x];
}

// K2: per-bucket exclusive scan over tile rows (in place), 16-way batched.
__global__ void __launch_bounds__(64) scan_tiles_k(uint32_t* __restrict__ hist,
                                                   uint32_t* __restrict__ totals) {
    int q = blockIdx.x * 64 + threadIdx.x;   // 16 * 64 = 1024
    uint32_t run = 0;
    for (int t0 = 0; t0 < NTILE; t0 += 16) {
        uint32_t vv[16];
        #pragma unroll
        for (int e = 0; e < 16; ++e) {
            int t = t0 + e;
            vv[e] = (t < NTILE) ? hist[(size_t)t * NBQ + q] : 0u;
        }
        #pragma unroll
        for (int e = 0; e < 16; ++e) {
            int t = t0 + e;
            if (t < NTILE) hist[(size_t)t * NBQ + q] = run;
            run += vv[e];
        }
    }
    totals[q] = run;
}

// K3: exclusive scan of 1024 totals -> base (single block)
__global__ void __launch_bounds__(256) scan_base_k(const uint32_t* __restrict__ totals,
                                                   uint32_t* __restrict__ base) {
    __shared__ uint32_t ssum[256];
    uint32_t loc[4];
    int q0 = threadIdx.x * 4;
    uint32_t s = 0;
    #pragma unroll
    for (int e = 0; e < 4; ++e) { loc[e] = totals[q0 + e]; s += loc[e]; }
    ssum[threadIdx.x] = s;
    __syncthreads();
    for (int off = 1; off < 256; off <<= 1) {
        uint32_t v = 0;
        if (threadIdx.x >= off) v = ssum[threadIdx.x - off];
        __syncthreads();
        if (threadIdx.x >= off) ssum[threadIdx.x] += v;
        __syncthreads();
    }
    uint32_t run = threadIdx.x ? ssum[threadIdx.x - 1] : 0;
    #pragma unroll
    for (int e = 0; e < 4; ++e) { base[q0 + e] = run; run += loc[e]; }
}

// K4: block-local counting sort; aux+val in registers; shuffle block scan;
// near-coalesced 4B record writeout.
__global__ void __launch_bounds__(1024, 8) reorder_k(const uint32_t* __restrict__ aux,
                                                     const float* __restrict__ val,
                                                     const uint32_t* __restrict__ hist,
                                                     const uint32_t* __restrict__ base,
                                                     uint32_t* __restrict__ rec) {
    __shared__ uint32_t h[NBQ];     // counts -> placement cursors
    __shared__ uint32_t gb[NBQ];    // gb[q] = base[q] + offrow[q] - lstart[q]
    __shared__ uint32_t wtot[16];
    __shared__ uint16_t sq[TP];     // bucket of sorted slot
    __shared__ uint32_t srt[TP];    // sorted packed records
    int tile = blockIdx.x;
    int p0 = tile * TP;
    int cnt = min(TP, NPTS - p0);
    h[threadIdx.x] = 0;
    __syncthreads();
    uint32_t a[8]; float v[8];
    #pragma unroll
    for (int e = 0; e < 8; ++e) {
        int r = threadIdx.x + e * 1024;
        if (r < cnt) {
            a[e] = aux[p0 + r];
            v[e] = val[p0 + r];
            atomicAdd(&h[a[e] >> 14], 1u);
        } else a[e] = 0xFFFFFFFFu;
    }
    __syncthreads();
    int q = threadIdx.x, lane = q & 63, wave = q >> 6;
    uint32_t cq = h[q];
    uint32_t inc = cq;
    #pragma unroll
    for (int off = 1; off < 64; off <<= 1) {
        uint32_t n = __shfl_up(inc, off, 64);
        if (lane >= off) inc += n;
    }
    if (lane == 63) wtot[wave] = inc;
    __syncthreads();
    if (q < 16) {
        uint32_t w = wtot[q];
        #pragma unroll
        for (int off = 1; off < 16; off <<= 1) {
            uint32_t n = __shfl_up(w, off, 16);
            if (q >= off) w += n;
        }
        wtot[q] = w;
    }
    __syncthreads();
    uint32_t lstart = (wave ? wtot[wave - 1] : 0u) + inc - cq;
    gb[q] = base[q] + hist[(size_t)tile * NBQ + q] - lstart;
    h[q] = lstart;
    __syncthreads();
    #pragma unroll
    for (int e = 0; e < 8; ++e) {
        if (a[e] != 0xFFFFFFFFu) {
            uint32_t qq = a[e] >> 14;
            uint32_t u = (__float_as_uint(v[e]) + 0x2000u) & 0xFFFFC000u;
            uint32_t pos = atomicAdd(&h[qq], 1u);
            srt[pos] = u | (a[e] & 16383u);
            sq[pos]  = (uint16_t)qq;
        }
    }
    __syncthreads();
    for (int t = threadIdx.x; t < cnt; t += 1024)
        rec[gb[sq[t]] + t] = srt[t];
}

// K5: per-bucket LDS accumulate (swizzled 64 KB) + k-line stencil + faces.
__global__ void __launch_bounds__(1024, 8) accum_k(const uint32_t* __restrict__ rec,
                                                   const uint32_t* __restrict__ base,
                                                   const uint32_t* __restrict__ totals,
                                                   float* __restrict__ faces,
                                                   float2* __restrict__ pa) {
    __shared__ float g[16384];   // swizzled: voxel (s=il*32+jl, kl) at gaddr(s,kl)
    int qb = blockIdx.x;
    {
        float4 z = make_float4(0.f, 0.f, 0.f, 0.f);
        #pragma unroll
        for (int c = 0; c < 4; ++c)
            *(float4*)&g[(threadIdx.x + c * 1024) * 4] = z;
    }
    __syncthreads();
    uint32_t s0 = base[qb], cnt = totals[qb];
    for (uint32_t r = threadIdx.x; r < cnt; r += 1024) {
        uint32_t e = rec[s0 + r];
        int l = e & 16383;
        atomicAdd(&g[gaddr(l >> 4, l & 15)], __uint_as_float(e & 0xFFFFC000u));
    }
    __syncthreads();
    // stencil: thread t owns line s = t (il = t>>5, jl = t&31)
    float tv = 0.f, mse = 0.f;
    {
        int s = threadIdx.x;
        int jl = s & 31, il = s >> 5;
        bool jin = jl < 31, iin = il < 31;
        float own[16];
        #pragma unroll
        for (int c = 0; c < 4; ++c)
            *(float4*)&own[c * 4] = *(const float4*)&g[s * 16 + goff(s, c)];
        #pragma unroll
        for (int k = 0; k < 15; ++k) {
            float d = own[k + 1] - own[k]; tv += fabsf(d); mse += d * d;
        }
        #pragma unroll
        for (int h = 0; h < 2; ++h) {
            if (jin) {
                float jn[8];
                *(float4*)&jn[0] = *(const float4*)&g[(s + 1) * 16 + goff(s + 1, 2 * h)];
                *(float4*)&jn[4] = *(const float4*)&g[(s + 1) * 16 + goff(s + 1, 2 * h + 1)];
                #pragma unroll
                for (int k = 0; k < 8; ++k) {
                    float d = jn[k] - own[8 * h + k]; tv += fabsf(d); mse += d * d;
                }
            }
            if (iin) {
                float inb[8];
                *(float4*)&inb[0] = *(const float4*)&g[(s + 32) * 16 + goff(s + 32, 2 * h)];
                *(float4*)&inb[4] = *(const float4*)&g[(s + 32) * 16 + goff(s + 32, 2 * h + 1)];
                #pragma unroll
                for (int k = 0; k < 8; ++k) {
                    float d = inb[k] - own[8 * h + k]; tv += fabsf(d); mse += d * d;
                }
            }
        }
    }
    // faces: [q][ i0:512 | i31:512 | j0:512 | j31:512 | k0:1024 | k15:1024 ]
    {
        float* f = faces + (size_t)qb * 4096;
        int t = threadIdx.x;
        if (t < 512) {
            int hi = t >> 4, lo = t & 15;
            f[t]        = g[gaddr(hi, lo)];             // i=0  (e = jl*16+kl)
            f[512 + t]  = g[gaddr(992 + hi, lo)];       // i=31
            f[1024 + t] = g[gaddr(hi * 32, lo)];        // j=0  (e = il*16+kl)
            f[1536 + t] = g[gaddr(hi * 32 + 31, lo)];   // j=31
        }
        f[2048 + t] = g[gaddr(t, 0)];                   // k=0  (e = il*32+jl = s)
        f[3072 + t] = g[gaddr(t, 15)];                  // k=15
    }
    block_reduce2<1024>(tv, mse);
    if (threadIdx.x == 0) pa[qb] = make_float2(tv, mse);
}

// K6: cross-sub-block interface diffs from face arrays (batch-major partials)
__global__ void __launch_bounds__(256) boundary_k(const float* __restrict__ faces,
                                                  float2* __restrict__ pb) {
    int x = blockIdx.x;
    int b = x / NIFACE;
    int r = x - b * NIFACE;
    int qA, qB, fA, fB, elems;
    if (r < 96) {                       // axis i
        int s = r >> 5, u = (r >> 3) & 3, w = r & 7;
        qA = (b << 7) | (s << 5) | (u << 3) | w; qB = qA + 32;
        fA = 512; fB = 0; elems = 512;
    } else if (r < 192) {               // axis j
        int r2 = r - 96;
        int s = r2 >> 5, u = (r2 >> 3) & 3, w = r2 & 7;
        qA = (b << 7) | (u << 5) | (s << 3) | w; qB = qA + 8;
        fA = 1536; fB = 1024; elems = 512;
    } else {                            // axis k
        int r2 = r - 192;
        int s = r2 >> 4, u = (r2 >> 2) & 3, v = r2 & 3;
        qA = (b << 7) | (u << 5) | (v << 3) | s; qB = qA + 1;
        fA = 3072; fB = 2048; elems = 1024;
    }
    const float* pA = faces + (size_t)qA * 4096 + fA;
    const float* pB = faces + (size_t)qB * 4096 + fB;
    float tv = 0.f, mse = 0.f;
    for (int e = threadIdx.x; e < elems; e += 256) {
        float d = pB[e] - pA[e];
        tv += fabsf(d); mse += d * d;
    }
    block_reduce2<256>(tv, mse);
    if (threadIdx.x == 0) pb[x] = make_float2(tv, mse);
}

// K7: final reduction — one block per batch, no atomics
__global__ void __launch_bounds__(256) final_k(const float2* __restrict__ pa,
                                               const float2* __restrict__ pb,
                                               float* __restrict__ out) {
    int b = blockIdx.x;
    float tv = 0.f, mse = 0.f;
    const float2* a = pa + (size_t)b * (NBQ / BATCH);
    for (int i = threadIdx.x; i < NBQ / BATCH; i += 256) { float2 v = a[i]; tv += v.x; mse += v.y; }
    const float2* p = pb + (size_t)b * NIFACE;
    for (int i = threadIdx.x; i < NIFACE; i += 256) { float2 v = p[i]; tv += v.x; mse += v.y; }
    block_reduce2<256>(tv, mse);
    if (threadIdx.x == 0) {
        out[b]     = tv  * (1.f / 2097152.f);   // / X^3
        out[8 + b] = mse * (1.f / 32512.f);     // / (2X^2-2X)
    }
}

extern "C" void kernel_launch(void* const* d_in, const int* in_sizes, int n_in,
                              void* d_out, int out_size, void* d_ws, size_t ws_size,
                              hipStream_t stream) {
    const int*   indices = (const int*)d_in[0];   // (B, M, 3) int32
    const float* values  = (const float*)d_in[1]; // (B, M) float32
    float*       out     = (float*)d_out;         // (2, B) float32

    // workspace (~34 MiB): aux (16 MB) aliases faces (16 MB) — aux dead after
    // reorder_k; faces written only by the later accum_k.
    uint32_t* hist   = (uint32_t*)d_ws;                       // NTILE*NBQ  (2.0 MB)
    uint32_t* totals = hist + (size_t)NTILE * NBQ;            // NBQ
    uint32_t* base   = totals + NBQ;                          // NBQ
    float2*   pa     = (float2*)(base + NBQ);                 // NBQ        (8 KB)
    float2*   pb     = pa + NBQ;                              // NBND       (19 KB)
    uint32_t* rec    = (uint32_t*)(pb + NBND);                // NPTS       (16 MB)
    float*    faces  = (float*)(rec + NPTS);                  // NBQ*4096   (16 MB)
    uint32_t* aux    = (uint32_t*)faces;                      // NPTS       (16 MB, aliased)

    hist_k      <<<NTILE, 1024, 0, stream>>>(indices, hist, aux);
    scan_tiles_k<<<16,    64,   0, stream>>>(hist, totals);
    scan_base_k <<<1,     256,  0, stream>>>(totals, base);
    reorder_k   <<<NTILE, 1024, 0, stream>>>(aux, values, hist, base, rec);
    accum_k     <<<NBQ,   1024, 0, stream>>>(rec, base, totals, faces, pa);
    boundary_k  <<<NBND,  256,  0, stream>>>(faces, pb);
    final_k     <<<BATCH, 256,  0, stream>>>(pa, pb, out);
}